// Round 6
// baseline (849.464 us; speedup 1.0000x reference)
//
#include <hip/hip_runtime.h>
#include <hip/hip_bf16.h>
#include <math.h>

__device__ __forceinline__ float sigmoidf_(float x) {
    return 1.0f / (1.0f + expf(-x));
}

// Butterfly sum across each 4-lane quad via DPP quad_perm (VALU-rate, no LDS).
// After this, all 4 lanes of the quad hold the full sum.
__device__ __forceinline__ float quad_sum(float v) {
    int a = __builtin_amdgcn_mov_dpp(__builtin_bit_cast(int, v), 0xB1, 0xF, 0xF, true); // [1,0,3,2]
    v += __builtin_bit_cast(float, a);
    int b = __builtin_amdgcn_mov_dpp(__builtin_bit_cast(int, v), 0x4E, 0xF, 0xF, true); // [2,3,0,1]
    v += __builtin_bit_cast(float, b);
    return v;
}

// ---------------------------------------------------------------------------
// Degree histogram over col (destination) indices. deg must be zeroed first.
// ---------------------------------------------------------------------------
__global__ void k_deg(const int* __restrict__ col, int* __restrict__ deg, int E) {
    int e = blockIdx.x * 256 + threadIdx.x;
    if (e < E) atomicAdd(&deg[col[e]], 1);
}

// dinv[n] = 1/sqrt(deg[n] + 1)   (+1 for the self loop; always > 0)
__global__ void k_dinv(const int* __restrict__ deg, float* __restrict__ dinv, int n) {
    int i = blockIdx.x * 256 + threadIdx.x;
    if (i < n) dinv[i] = 1.0f / sqrtf((float)(deg[i] + 1));
}

// ---------------------------------------------------------------------------
// Hierarchical exclusive scan of deg -> off (CSR row offsets).
// ---------------------------------------------------------------------------
__global__ __launch_bounds__(256) void k_scan1(const int* __restrict__ deg,
        int* __restrict__ off, int* __restrict__ bsum, int n) {
    __shared__ int tmp[256];
    int tid = threadIdx.x;
    int i = blockIdx.x * 256 + tid;
    int v = (i < n) ? deg[i] : 0;
    tmp[tid] = v;
    __syncthreads();
#pragma unroll
    for (int s = 1; s < 256; s <<= 1) {
        int t = (tid >= s) ? tmp[tid - s] : 0;
        __syncthreads();
        tmp[tid] += t;
        __syncthreads();
    }
    if (i < n) off[i] = tmp[tid] - v;             // block-local exclusive
    if (tid == 255) bsum[blockIdx.x] = tmp[255];  // block total
}

__global__ __launch_bounds__(1024) void k_scan2(const int* __restrict__ bsum,
        int* __restrict__ bscan, int nb) {
    __shared__ int tmp[1024];
    int tid = threadIdx.x;
    int v = (tid < nb) ? bsum[tid] : 0;
    tmp[tid] = v;
    __syncthreads();
#pragma unroll
    for (int s = 1; s < 1024; s <<= 1) {
        int t = (tid >= s) ? tmp[tid - s] : 0;
        __syncthreads();
        tmp[tid] += t;
        __syncthreads();
    }
    if (tid < nb) bscan[tid] = tmp[tid] - v;
}

__global__ __launch_bounds__(256) void k_scan3(int* __restrict__ off,
        const int* __restrict__ bscan, const int* __restrict__ deg,
        int* __restrict__ cur, int n) {
    int i = blockIdx.x * 256 + threadIdx.x;
    if (i >= n) return;
    int o = off[i] + bscan[blockIdx.x];
    off[i] = o;
    cur[i] = o;
    if (i == n - 1) off[n] = o + deg[i];
}

// Fill CSR neighbor lists (grouped by destination, stores source index).
__global__ void k_fill(const int* __restrict__ row, const int* __restrict__ col,
                       int* __restrict__ cur, int* __restrict__ nbr, int E) {
    int e = blockIdx.x * 256 + threadIdx.x;
    if (e < E) {
        int c = col[e];
        int p = atomicAdd(&cur[c], 1);
        nbr[p] = row[e];
    }
}

// ---------------------------------------------------------------------------
// Fused LSTM step + (h @ W1), 4 threads per node (k/s-split).
// Lane jg = t&3 owns k-slice [16jg,16jg+16) of x and s-slice [16jg,16jg+16)
// of the output. Gates: partial dots over the k-slice, quad_sum (DPP) to
// full sums, transcendentals computed redundantly on all 4 lanes, then each
// lane accumulates its own 16-wide W1 slice. No output reduction.
//   gates = x @ W_ih^T + b_ih + b_hh   (f gate dead: c0 = 0)
//   c = sig(i)*tanh(g); h = sig(o)*tanh(c);  hw1 = h @ W1
// ---------------------------------------------------------------------------
__global__ __launch_bounds__(256) void k_lstm_mm1(
    const float* __restrict__ x, const float* __restrict__ Wih,
    const float* __restrict__ bih, const float* __restrict__ bhh,
    const float* __restrict__ W1, float* __restrict__ hw1, int n)
{
    int t = blockIdx.x * 256 + threadIdx.x;
    int node = t >> 2;
    int jg   = t & 3;
    if (node >= n) return;
    int kbase = jg * 16;

    float xr[16];
    const float4* xp = reinterpret_cast<const float4*>(x + (size_t)node * 64 + kbase);
#pragma unroll
    for (int q = 0; q < 4; q++) {
        float4 v = xp[q];
        xr[4*q+0] = v.x; xr[4*q+1] = v.y; xr[4*q+2] = v.z; xr[4*q+3] = v.w;
    }

    float acc[16];
#pragma unroll
    for (int s = 0; s < 16; s++) acc[s] = 0.0f;

#pragma unroll 2
    for (int j = 0; j < 64; j++) {
        const float4* wi = reinterpret_cast<const float4*>(Wih + (size_t)j * 64 + kbase);
        const float4* wg = reinterpret_cast<const float4*>(Wih + (size_t)(128 + j) * 64 + kbase);
        const float4* wo = reinterpret_cast<const float4*>(Wih + (size_t)(192 + j) * 64 + kbase);
        float gi = 0.0f, gg = 0.0f, go = 0.0f;
#pragma unroll
        for (int q = 0; q < 4; q++) {
            float4 a = wi[q], b = wg[q], c4 = wo[q];
            float x0 = xr[4*q+0], x1 = xr[4*q+1], x2 = xr[4*q+2], x3 = xr[4*q+3];
            gi = fmaf(x0, a.x, gi);  gi = fmaf(x1, a.y, gi);
            gi = fmaf(x2, a.z, gi);  gi = fmaf(x3, a.w, gi);
            gg = fmaf(x0, b.x, gg);  gg = fmaf(x1, b.y, gg);
            gg = fmaf(x2, b.z, gg);  gg = fmaf(x3, b.w, gg);
            go = fmaf(x0, c4.x, go); go = fmaf(x1, c4.y, go);
            go = fmaf(x2, c4.z, go); go = fmaf(x3, c4.w, go);
        }
        gi = quad_sum(gi) + bih[j]       + bhh[j];
        gg = quad_sum(gg) + bih[128 + j] + bhh[128 + j];
        go = quad_sum(go) + bih[192 + j] + bhh[192 + j];

        float c  = sigmoidf_(gi) * tanhf(gg);
        float hj = sigmoidf_(go) * tanhf(c);

        const float4* w1r = reinterpret_cast<const float4*>(W1 + (size_t)j * 64 + kbase);
#pragma unroll
        for (int q = 0; q < 4; q++) {
            float4 w = w1r[q];
            acc[4*q+0] = fmaf(hj, w.x, acc[4*q+0]);
            acc[4*q+1] = fmaf(hj, w.y, acc[4*q+1]);
            acc[4*q+2] = fmaf(hj, w.z, acc[4*q+2]);
            acc[4*q+3] = fmaf(hj, w.w, acc[4*q+3]);
        }
    }

    float4* op = reinterpret_cast<float4*>(hw1 + (size_t)node * 64 + kbase);
#pragma unroll
    for (int q = 0; q < 4; q++)
        op[q] = make_float4(acc[4*q], acc[4*q+1], acc[4*q+2], acc[4*q+3]);
}

// ---------------------------------------------------------------------------
// Pull aggregation, F=64. One wave per node, lane = feature.
// Fused epilogue 1: h1 = relu(agg*dc + hw1[node]*dc^2 + b1)
// ---------------------------------------------------------------------------
__global__ __launch_bounds__(256) void k_pull64(
    const float* __restrict__ hw, const int* __restrict__ off,
    const int* __restrict__ nbr, const float* __restrict__ dinv,
    const float* __restrict__ b1, float* __restrict__ h1, int n)
{
    int node = (blockIdx.x * 256 + threadIdx.x) >> 6;
    int lane = threadIdx.x & 63;
    if (node >= n) return;
    int s = off[node], e = off[node + 1];
    float a0 = 0.0f, a1 = 0.0f;
    int j = s;
    for (; j + 2 <= e; j += 2) {           // 2 neighbors in flight
        int r0 = nbr[j], r1 = nbr[j + 1];
        float w0 = dinv[r0], w1 = dinv[r1];
        a0 = fmaf(hw[(size_t)r0 * 64 + lane], w0, a0);
        a1 = fmaf(hw[(size_t)r1 * 64 + lane], w1, a1);
    }
    if (j < e) {
        int r0 = nbr[j];
        a0 = fmaf(hw[(size_t)r0 * 64 + lane], dinv[r0], a0);
    }
    float dc   = dinv[node];
    float self = hw[(size_t)node * 64 + lane];
    float v = (a0 + a1) * dc + self * dc * dc + b1[lane];
    h1[(size_t)node * 64 + lane] = fmaxf(v, 0.0f);
}

// ---------------------------------------------------------------------------
// Pull aggregation, F=32. One wave per node; lanes 0-31 even neighbors,
// lanes 32-63 odd neighbors; halves combined via shfl_xor 32.
// Fused epilogue 2: z = agg*dc + hw2[node]*dc^2 + b2  (no relu)
// ---------------------------------------------------------------------------
__global__ __launch_bounds__(256) void k_pull32(
    const float* __restrict__ hw, const int* __restrict__ off,
    const int* __restrict__ nbr, const float* __restrict__ dinv,
    const float* __restrict__ b2, float* __restrict__ z, int n)
{
    int node = (blockIdx.x * 256 + threadIdx.x) >> 6;
    int lane = threadIdx.x & 63;
    int feat = lane & 31;
    int half = lane >> 5;
    if (node >= n) return;
    int s = off[node], e = off[node + 1];
    float acc = 0.0f;
    for (int j = s + half; j < e; j += 2) {
        int r = nbr[j];
        acc = fmaf(hw[(size_t)r * 32 + feat], dinv[r], acc);
    }
    acc += __shfl_xor(acc, 32, 64);        // combine even/odd halves
    float dc = dinv[node];
    float v = acc * dc + hw[(size_t)node * 32 + feat] * dc * dc + b2[feat];
    if (half == 0) z[(size_t)node * 32 + feat] = v;
}

// ---------------------------------------------------------------------------
// hw2 = h1 @ W2  ([n,64] x [64,32]). Block = 128 nodes, h1 tile in LDS (pad 65).
// ---------------------------------------------------------------------------
__global__ __launch_bounds__(128) void k_mm2(
    const float* __restrict__ h1, const float* __restrict__ W2,
    float* __restrict__ hw2, int n)
{
    __shared__ float tile[128 * 65];
    int base  = blockIdx.x * 128;
    int nrows = n - base; if (nrows > 128) nrows = 128;

    for (int idx = threadIdx.x; idx < nrows * 64; idx += 128) {
        int r = idx >> 6, c = idx & 63;
        tile[r * 65 + c] = h1[(size_t)base * 64 + idx];
    }
    __syncthreads();

    int node = base + threadIdx.x;
    if (node >= n) return;

    const float* hrow = &tile[threadIdx.x * 65];
    float acc[32];
#pragma unroll
    for (int s = 0; s < 32; s++) acc[s] = 0.0f;

    for (int k = 0; k < 64; k++) {
        float hk = hrow[k];
        const float* w = W2 + (size_t)k * 32;
#pragma unroll
        for (int s = 0; s < 32; s++) acc[s] = fmaf(hk, w[s], acc[s]);
    }

    float4* op = reinterpret_cast<float4*>(hw2 + (size_t)node * 32);
#pragma unroll
    for (int q = 0; q < 8; q++)
        op[q] = make_float4(acc[4*q], acc[4*q+1], acc[4*q+2], acc[4*q+3]);
}

// ---------------------------------------------------------------------------
// out[e] = dot(z[src[e]], z[dst[e]]) over 32 features
// ---------------------------------------------------------------------------
__global__ void k_dot(const float* __restrict__ z, const int* __restrict__ src,
                      const int* __restrict__ dst, float* __restrict__ out, int EL)
{
    int e = blockIdx.x * 256 + threadIdx.x;
    if (e >= EL) return;
    const float4* a = reinterpret_cast<const float4*>(z + (size_t)src[e] * 32);
    const float4* b = reinterpret_cast<const float4*>(z + (size_t)dst[e] * 32);
    float s = 0.0f;
#pragma unroll
    for (int q = 0; q < 8; q++) {
        float4 av = a[q], bv = b[q];
        s = fmaf(av.x, bv.x, s);
        s = fmaf(av.y, bv.y, s);
        s = fmaf(av.z, bv.z, s);
        s = fmaf(av.w, bv.w, s);
    }
    out[e] = s;
}

extern "C" void kernel_launch(void* const* d_in, const int* in_sizes, int n_in,
                              void* d_out, int out_size, void* d_ws, size_t ws_size,
                              hipStream_t stream)
{
    const float* x   = (const float*)d_in[0];
    const int*   ei  = (const int*)d_in[1];
    const int*   eli = (const int*)d_in[2];
    const float* Wih = (const float*)d_in[3];
    // d_in[4] = W_hh: mathematically dead (h0 = c0 = 0)
    const float* bih = (const float*)d_in[5];
    const float* bhh = (const float*)d_in[6];
    const float* W1  = (const float*)d_in[7];
    const float* b1  = (const float*)d_in[8];
    const float* W2  = (const float*)d_in[9];
    const float* b2  = (const float*)d_in[10];

    int n  = in_sizes[0] / 64;
    int E  = in_sizes[1] / 2;
    int EL = in_sizes[2] / 2;

    const int* row  = ei;          // source
    const int* col  = ei + E;      // destination
    const int* lsrc = eli;
    const int* ldst = eli + EL;
    float* out = (float*)d_out;

    // Workspace layout (4B units), liveness-aliased:
    //   bufA [n*64]: hw1 (lstm..pull64), then hw2 in first n*32 (mm2..pull32)
    //   bufB [n*64]: h1  (pull64..mm2), then z   in first n*32 (pull32..dot)
    //   dinv [n] | off [n+1] | deg [n] | cur [n] | bsum [1024] | bscan [1024]
    //   nbr [E]   (~59.2 MB total)
    float* bufA  = (float*)d_ws;
    float* bufB  = bufA + (size_t)n * 64;
    float* dinv  = bufB + (size_t)n * 64;
    int*   off   = (int*)(dinv + n);
    int*   deg   = off + (n + 1);
    int*   cur   = deg + n;
    int*   bsum  = cur + n;
    int*   bscan = bsum + 1024;
    int*   nbr   = bscan + 1024;

    int nb = (n + 255) / 256;      // 391 for n=100000; k_scan2 handles nb<=1024
    dim3 blk(256);

    // --- CSR build (deterministic counting sort by destination) ---
    hipMemsetAsync(deg, 0, (size_t)n * sizeof(int), stream);
    k_deg  <<<dim3((E + 255) / 256), blk, 0, stream>>>(col, deg, E);
    k_dinv <<<dim3(nb), blk, 0, stream>>>(deg, dinv, n);
    k_scan1<<<dim3(nb), blk, 0, stream>>>(deg, off, bsum, n);
    k_scan2<<<dim3(1), dim3(1024), 0, stream>>>(bsum, bscan, nb);
    k_scan3<<<dim3(nb), blk, 0, stream>>>(off, bscan, deg, cur, n);
    k_fill <<<dim3((E + 255) / 256), blk, 0, stream>>>(row, col, cur, nbr, E);

    // --- LSTM + first matmul: hw1 -> bufA (4 threads per node) ---
    {
        int blocks = (int)(((size_t)n * 4 + 255) / 256);
        k_lstm_mm1<<<dim3(blocks), blk, 0, stream>>>(x, Wih, bih, bhh, W1, bufA, n);
    }

    // --- GCN1: pull + fused epilogue (relu) : h1 -> bufB ---
    {
        int blocks = (int)(((size_t)n * 64 + 255) / 256);
        k_pull64<<<dim3(blocks), blk, 0, stream>>>(bufA, off, nbr, dinv, b1, bufB, n);
    }

    // --- second matmul: hw2 -> bufA (hw1 dead) ---
    k_mm2<<<dim3((n + 127) / 128), dim3(128), 0, stream>>>(bufB, W2, bufA, n);

    // --- GCN2: pull + fused epilogue : z -> bufB (h1 dead) ---
    {
        int blocks = (int)(((size_t)n * 64 + 255) / 256);
        k_pull32<<<dim3(blocks), blk, 0, stream>>>(bufA, off, nbr, dinv, b2, bufB, n);
    }

    // --- edge dot products ---
    k_dot<<<dim3((EL + 255) / 256), blk, 0, stream>>>(bufB, lsrc, ldst, out, EL);
}

// Round 7
// 601.877 us; speedup vs baseline: 1.4114x; 1.4114x over previous
//
#include <hip/hip_runtime.h>
#include <hip/hip_bf16.h>
#include <math.h>

// Fast device transcendentals: native v_exp_f32 + v_rcp_f32.
// sigmoid(x) = 1 - 1/(1+e^x)   (safe for x -> +/-inf: rcp(inf)=0)
// tanh(x)    = 1 - 2/(1+e^2x)  (safe both ends)
__device__ __forceinline__ float fast_sigmoid(float x) {
    float t = __expf(x);
    return 1.0f - __builtin_amdgcn_rcpf(1.0f + t);
}
__device__ __forceinline__ float fast_tanh(float x) {
    float t = __expf(2.0f * x);
    return 1.0f - 2.0f * __builtin_amdgcn_rcpf(1.0f + t);
}

// ---------------------------------------------------------------------------
// Degree histogram over col (destination) indices. deg must be zeroed first.
// ---------------------------------------------------------------------------
__global__ void k_deg(const int* __restrict__ col, int* __restrict__ deg, int E) {
    int e = blockIdx.x * 256 + threadIdx.x;
    if (e < E) atomicAdd(&deg[col[e]], 1);
}

// dinv[n] = 1/sqrt(deg[n] + 1)   (+1 for the self loop; always > 0)
__global__ void k_dinv(const int* __restrict__ deg, float* __restrict__ dinv, int n) {
    int i = blockIdx.x * 256 + threadIdx.x;
    if (i < n) dinv[i] = 1.0f / sqrtf((float)(deg[i] + 1));
}

// ---------------------------------------------------------------------------
// Hierarchical exclusive scan of deg -> off (CSR row offsets).
// ---------------------------------------------------------------------------
__global__ __launch_bounds__(256) void k_scan1(const int* __restrict__ deg,
        int* __restrict__ off, int* __restrict__ bsum, int n) {
    __shared__ int tmp[256];
    int tid = threadIdx.x;
    int i = blockIdx.x * 256 + tid;
    int v = (i < n) ? deg[i] : 0;
    tmp[tid] = v;
    __syncthreads();
#pragma unroll
    for (int s = 1; s < 256; s <<= 1) {
        int t = (tid >= s) ? tmp[tid - s] : 0;
        __syncthreads();
        tmp[tid] += t;
        __syncthreads();
    }
    if (i < n) off[i] = tmp[tid] - v;             // block-local exclusive
    if (tid == 255) bsum[blockIdx.x] = tmp[255];  // block total
}

__global__ __launch_bounds__(1024) void k_scan2(const int* __restrict__ bsum,
        int* __restrict__ bscan, int nb) {
    __shared__ int tmp[1024];
    int tid = threadIdx.x;
    int v = (tid < nb) ? bsum[tid] : 0;
    tmp[tid] = v;
    __syncthreads();
#pragma unroll
    for (int s = 1; s < 1024; s <<= 1) {
        int t = (tid >= s) ? tmp[tid - s] : 0;
        __syncthreads();
        tmp[tid] += t;
        __syncthreads();
    }
    if (tid < nb) bscan[tid] = tmp[tid] - v;
}

__global__ __launch_bounds__(256) void k_scan3(int* __restrict__ off,
        const int* __restrict__ bscan, const int* __restrict__ deg,
        int* __restrict__ cur, int n) {
    int i = blockIdx.x * 256 + threadIdx.x;
    if (i >= n) return;
    int o = off[i] + bscan[blockIdx.x];
    off[i] = o;
    cur[i] = o;
    if (i == n - 1) off[n] = o + deg[i];
}

// Fill CSR neighbor lists (grouped by destination, stores source index).
__global__ void k_fill(const int* __restrict__ row, const int* __restrict__ col,
                       int* __restrict__ cur, int* __restrict__ nbr, int E) {
    int e = blockIdx.x * 256 + threadIdx.x;
    if (e < E) {
        int c = col[e];
        int p = atomicAdd(&cur[c], 1);
        nbr[p] = row[e];
    }
}

// ---------------------------------------------------------------------------
// Fused LSTM step + (h @ W1). ONE thread per node, 64-thread blocks.
// __launch_bounds__(64,2): VGPR cap 256 -> xr[64]+acc[64]+temps fully in
// registers (round-5's VGPR=72 proved the compiler was scratch-spilling).
// Each gate dot uses 4 partial accumulators -> 12 independent FMA chains of
// 16 instead of 3 chains of 64 (latency -> issue bound).
//   gates = x @ W_ih^T + b_ih + b_hh   (f gate dead: c0 = 0)
//   c = sig(i)*tanh(g); h = sig(o)*tanh(c);  hw1 = h @ W1
// ---------------------------------------------------------------------------
__global__ __launch_bounds__(64, 2) void k_lstm_mm1(
    const float* __restrict__ x, const float* __restrict__ Wih,
    const float* __restrict__ bih, const float* __restrict__ bhh,
    const float* __restrict__ W1, float* __restrict__ hw1, int n)
{
    int node = blockIdx.x * 64 + threadIdx.x;
    if (node >= n) return;

    float xr[64];
    const float4* xp = reinterpret_cast<const float4*>(x + (size_t)node * 64);
#pragma unroll
    for (int q = 0; q < 16; q++) {
        float4 v = xp[q];
        xr[4*q+0] = v.x; xr[4*q+1] = v.y; xr[4*q+2] = v.z; xr[4*q+3] = v.w;
    }

    float acc[64];
#pragma unroll
    for (int s = 0; s < 64; s++) acc[s] = 0.0f;

#pragma unroll 2
    for (int j = 0; j < 64; j++) {
        const float4* wi = reinterpret_cast<const float4*>(Wih + (size_t)j * 64);
        const float4* wg = reinterpret_cast<const float4*>(Wih + (size_t)(128 + j) * 64);
        const float4* wo = reinterpret_cast<const float4*>(Wih + (size_t)(192 + j) * 64);
        float i0 = 0.f, i1 = 0.f, i2 = 0.f, i3 = 0.f;
        float g0 = 0.f, g1 = 0.f, g2 = 0.f, g3 = 0.f;
        float o0 = 0.f, o1 = 0.f, o2 = 0.f, o3 = 0.f;
#pragma unroll
        for (int q = 0; q < 16; q++) {
            float4 a = wi[q], b = wg[q], c4 = wo[q];
            float x0 = xr[4*q+0], x1 = xr[4*q+1], x2 = xr[4*q+2], x3 = xr[4*q+3];
            i0 = fmaf(x0, a.x, i0);  i1 = fmaf(x1, a.y, i1);
            i2 = fmaf(x2, a.z, i2);  i3 = fmaf(x3, a.w, i3);
            g0 = fmaf(x0, b.x, g0);  g1 = fmaf(x1, b.y, g1);
            g2 = fmaf(x2, b.z, g2);  g3 = fmaf(x3, b.w, g3);
            o0 = fmaf(x0, c4.x, o0); o1 = fmaf(x1, c4.y, o1);
            o2 = fmaf(x2, c4.z, o2); o3 = fmaf(x3, c4.w, o3);
        }
        float gi = (i0 + i1) + (i2 + i3) + (bih[j]       + bhh[j]);
        float gg = (g0 + g1) + (g2 + g3) + (bih[128 + j] + bhh[128 + j]);
        float go = (o0 + o1) + (o2 + o3) + (bih[192 + j] + bhh[192 + j]);

        float c  = fast_sigmoid(gi) * fast_tanh(gg);
        float hj = fast_sigmoid(go) * fast_tanh(c);

        const float4* w1r = reinterpret_cast<const float4*>(W1 + (size_t)j * 64);
#pragma unroll
        for (int q = 0; q < 16; q++) {
            float4 w = w1r[q];
            acc[4*q+0] = fmaf(hj, w.x, acc[4*q+0]);
            acc[4*q+1] = fmaf(hj, w.y, acc[4*q+1]);
            acc[4*q+2] = fmaf(hj, w.z, acc[4*q+2]);
            acc[4*q+3] = fmaf(hj, w.w, acc[4*q+3]);
        }
    }

    float4* op = reinterpret_cast<float4*>(hw1 + (size_t)node * 64);
#pragma unroll
    for (int q = 0; q < 16; q++)
        op[q] = make_float4(acc[4*q], acc[4*q+1], acc[4*q+2], acc[4*q+3]);
}

// ---------------------------------------------------------------------------
// Pull aggregation, F=64. One wave per node, lane = feature.
// Fused epilogue 1: h1 = relu(agg*dc + hw1[node]*dc^2 + b1)
// ---------------------------------------------------------------------------
__global__ __launch_bounds__(256) void k_pull64(
    const float* __restrict__ hw, const int* __restrict__ off,
    const int* __restrict__ nbr, const float* __restrict__ dinv,
    const float* __restrict__ b1, float* __restrict__ h1, int n)
{
    int node = (blockIdx.x * 256 + threadIdx.x) >> 6;
    int lane = threadIdx.x & 63;
    if (node >= n) return;
    int s = off[node], e = off[node + 1];
    float a0 = 0.0f, a1 = 0.0f;
    int j = s;
    for (; j + 2 <= e; j += 2) {           // 2 neighbors in flight
        int r0 = nbr[j], r1 = nbr[j + 1];
        float w0 = dinv[r0], w1 = dinv[r1];
        a0 = fmaf(hw[(size_t)r0 * 64 + lane], w0, a0);
        a1 = fmaf(hw[(size_t)r1 * 64 + lane], w1, a1);
    }
    if (j < e) {
        int r0 = nbr[j];
        a0 = fmaf(hw[(size_t)r0 * 64 + lane], dinv[r0], a0);
    }
    float dc   = dinv[node];
    float self = hw[(size_t)node * 64 + lane];
    float v = (a0 + a1) * dc + self * dc * dc + b1[lane];
    h1[(size_t)node * 64 + lane] = fmaxf(v, 0.0f);
}

// ---------------------------------------------------------------------------
// Pull aggregation, F=32. One wave per node; lanes 0-31 even neighbors,
// lanes 32-63 odd neighbors; halves combined via shfl_xor 32.
// Fused epilogue 2: z = agg*dc + hw2[node]*dc^2 + b2  (no relu)
// ---------------------------------------------------------------------------
__global__ __launch_bounds__(256) void k_pull32(
    const float* __restrict__ hw, const int* __restrict__ off,
    const int* __restrict__ nbr, const float* __restrict__ dinv,
    const float* __restrict__ b2, float* __restrict__ z, int n)
{
    int node = (blockIdx.x * 256 + threadIdx.x) >> 6;
    int lane = threadIdx.x & 63;
    int feat = lane & 31;
    int half = lane >> 5;
    if (node >= n) return;
    int s = off[node], e = off[node + 1];
    float acc = 0.0f;
    for (int j = s + half; j < e; j += 2) {
        int r = nbr[j];
        acc = fmaf(hw[(size_t)r * 32 + feat], dinv[r], acc);
    }
    acc += __shfl_xor(acc, 32, 64);        // combine even/odd halves
    float dc = dinv[node];
    float v = acc * dc + hw[(size_t)node * 32 + feat] * dc * dc + b2[feat];
    if (half == 0) z[(size_t)node * 32 + feat] = v;
}

// ---------------------------------------------------------------------------
// hw2 = h1 @ W2  ([n,64] x [64,32]). Block = 128 nodes, h1 tile in LDS (pad 65).
// ---------------------------------------------------------------------------
__global__ __launch_bounds__(128) void k_mm2(
    const float* __restrict__ h1, const float* __restrict__ W2,
    float* __restrict__ hw2, int n)
{
    __shared__ float tile[128 * 65];
    int base  = blockIdx.x * 128;
    int nrows = n - base; if (nrows > 128) nrows = 128;

    for (int idx = threadIdx.x; idx < nrows * 64; idx += 128) {
        int r = idx >> 6, c = idx & 63;
        tile[r * 65 + c] = h1[(size_t)base * 64 + idx];
    }
    __syncthreads();

    int node = base + threadIdx.x;
    if (node >= n) return;

    const float* hrow = &tile[threadIdx.x * 65];
    float acc[32];
#pragma unroll
    for (int s = 0; s < 32; s++) acc[s] = 0.0f;

    for (int k = 0; k < 64; k++) {
        float hk = hrow[k];
        const float* w = W2 + (size_t)k * 32;
#pragma unroll
        for (int s = 0; s < 32; s++) acc[s] = fmaf(hk, w[s], acc[s]);
    }

    float4* op = reinterpret_cast<float4*>(hw2 + (size_t)node * 32);
#pragma unroll
    for (int q = 0; q < 8; q++)
        op[q] = make_float4(acc[4*q], acc[4*q+1], acc[4*q+2], acc[4*q+3]);
}

// ---------------------------------------------------------------------------
// out[e] = dot(z[src[e]], z[dst[e]]) over 32 features
// ---------------------------------------------------------------------------
__global__ void k_dot(const float* __restrict__ z, const int* __restrict__ src,
                      const int* __restrict__ dst, float* __restrict__ out, int EL)
{
    int e = blockIdx.x * 256 + threadIdx.x;
    if (e >= EL) return;
    const float4* a = reinterpret_cast<const float4*>(z + (size_t)src[e] * 32);
    const float4* b = reinterpret_cast<const float4*>(z + (size_t)dst[e] * 32);
    float s = 0.0f;
#pragma unroll
    for (int q = 0; q < 8; q++) {
        float4 av = a[q], bv = b[q];
        s = fmaf(av.x, bv.x, s);
        s = fmaf(av.y, bv.y, s);
        s = fmaf(av.z, bv.z, s);
        s = fmaf(av.w, bv.w, s);
    }
    out[e] = s;
}

extern "C" void kernel_launch(void* const* d_in, const int* in_sizes, int n_in,
                              void* d_out, int out_size, void* d_ws, size_t ws_size,
                              hipStream_t stream)
{
    const float* x   = (const float*)d_in[0];
    const int*   ei  = (const int*)d_in[1];
    const int*   eli = (const int*)d_in[2];
    const float* Wih = (const float*)d_in[3];
    // d_in[4] = W_hh: mathematically dead (h0 = c0 = 0)
    const float* bih = (const float*)d_in[5];
    const float* bhh = (const float*)d_in[6];
    const float* W1  = (const float*)d_in[7];
    const float* b1  = (const float*)d_in[8];
    const float* W2  = (const float*)d_in[9];
    const float* b2  = (const float*)d_in[10];

    int n  = in_sizes[0] / 64;
    int E  = in_sizes[1] / 2;
    int EL = in_sizes[2] / 2;

    const int* row  = ei;          // source
    const int* col  = ei + E;      // destination
    const int* lsrc = eli;
    const int* ldst = eli + EL;
    float* out = (float*)d_out;

    // Workspace layout (4B units), liveness-aliased:
    //   bufA [n*64]: hw1 (lstm..pull64), then hw2 in first n*32 (mm2..pull32)
    //   bufB [n*64]: h1  (pull64..mm2), then z   in first n*32 (pull32..dot)
    //   dinv [n] | off [n+1] | deg [n] | cur [n] | bsum [1024] | bscan [1024]
    //   nbr [E]   (~59.2 MB total)
    float* bufA  = (float*)d_ws;
    float* bufB  = bufA + (size_t)n * 64;
    float* dinv  = bufB + (size_t)n * 64;
    int*   off   = (int*)(dinv + n);
    int*   deg   = off + (n + 1);
    int*   cur   = deg + n;
    int*   bsum  = cur + n;
    int*   bscan = bsum + 1024;
    int*   nbr   = bscan + 1024;

    int nb = (n + 255) / 256;      // 391 for n=100000; k_scan2 handles nb<=1024
    dim3 blk(256);

    // --- CSR build (deterministic counting sort by destination) ---
    hipMemsetAsync(deg, 0, (size_t)n * sizeof(int), stream);
    k_deg  <<<dim3((E + 255) / 256), blk, 0, stream>>>(col, deg, E);
    k_dinv <<<dim3(nb), blk, 0, stream>>>(deg, dinv, n);
    k_scan1<<<dim3(nb), blk, 0, stream>>>(deg, off, bsum, n);
    k_scan2<<<dim3(1), dim3(1024), 0, stream>>>(bsum, bscan, nb);
    k_scan3<<<dim3(nb), blk, 0, stream>>>(off, bscan, deg, cur, n);
    k_fill <<<dim3((E + 255) / 256), blk, 0, stream>>>(row, col, cur, nbr, E);

    // --- LSTM + first matmul: hw1 -> bufA (1 thread/node, 64-thread blocks) ---
    k_lstm_mm1<<<dim3((n + 63) / 64), dim3(64), 0, stream>>>(x, Wih, bih, bhh, W1, bufA, n);

    // --- GCN1: pull + fused epilogue (relu) : h1 -> bufB ---
    {
        int blocks = (int)(((size_t)n * 64 + 255) / 256);
        k_pull64<<<dim3(blocks), blk, 0, stream>>>(bufA, off, nbr, dinv, b1, bufB, n);
    }

    // --- second matmul: hw2 -> bufA (hw1 dead) ---
    k_mm2<<<dim3((n + 127) / 128), dim3(128), 0, stream>>>(bufB, W2, bufA, n);

    // --- GCN2: pull + fused epilogue : z -> bufB (h1 dead) ---
    {
        int blocks = (int)(((size_t)n * 64 + 255) / 256);
        k_pull32<<<dim3(blocks), blk, 0, stream>>>(bufA, off, nbr, dinv, b2, bufB, n);
    }

    // --- edge dot products ---
    k_dot<<<dim3((EL + 255) / 256), blk, 0, stream>>>(bufB, lsrc, ldst, out, EL);
}

// Round 8
// 505.259 us; speedup vs baseline: 1.6812x; 1.1912x over previous
//
#include <hip/hip_runtime.h>
#include <hip/hip_bf16.h>
#include <math.h>

// Fast device transcendentals: native v_exp_f32 + v_rcp_f32.
// sigmoid(x) = 1 - 1/(1+e^x)   (safe for x -> +/-inf: rcp(inf)=0)
// tanh(x)    = 1 - 2/(1+e^2x)  (safe both ends)
__device__ __forceinline__ float fast_sigmoid(float x) {
    float t = __expf(x);
    return 1.0f - __builtin_amdgcn_rcpf(1.0f + t);
}
__device__ __forceinline__ float fast_tanh(float x) {
    float t = __expf(2.0f * x);
    return 1.0f - 2.0f * __builtin_amdgcn_rcpf(1.0f + t);
}

// ---------------------------------------------------------------------------
// Degree histogram over col (destination) indices. deg must be zeroed first.
// ---------------------------------------------------------------------------
__global__ void k_deg(const int* __restrict__ col, int* __restrict__ deg, int E) {
    int e = blockIdx.x * 256 + threadIdx.x;
    if (e < E) atomicAdd(&deg[col[e]], 1);
}

// dinv[n] = 1/sqrt(deg[n] + 1)   (+1 for the self loop; always > 0)
__global__ void k_dinv(const int* __restrict__ deg, float* __restrict__ dinv, int n) {
    int i = blockIdx.x * 256 + threadIdx.x;
    if (i < n) dinv[i] = 1.0f / sqrtf((float)(deg[i] + 1));
}

// ---------------------------------------------------------------------------
// Hierarchical exclusive scan of deg -> off (CSR row offsets).
// ---------------------------------------------------------------------------
__global__ __launch_bounds__(256) void k_scan1(const int* __restrict__ deg,
        int* __restrict__ off, int* __restrict__ bsum, int n) {
    __shared__ int tmp[256];
    int tid = threadIdx.x;
    int i = blockIdx.x * 256 + tid;
    int v = (i < n) ? deg[i] : 0;
    tmp[tid] = v;
    __syncthreads();
#pragma unroll
    for (int s = 1; s < 256; s <<= 1) {
        int t = (tid >= s) ? tmp[tid - s] : 0;
        __syncthreads();
        tmp[tid] += t;
        __syncthreads();
    }
    if (i < n) off[i] = tmp[tid] - v;             // block-local exclusive
    if (tid == 255) bsum[blockIdx.x] = tmp[255];  // block total
}

__global__ __launch_bounds__(1024) void k_scan2(const int* __restrict__ bsum,
        int* __restrict__ bscan, int nb) {
    __shared__ int tmp[1024];
    int tid = threadIdx.x;
    int v = (tid < nb) ? bsum[tid] : 0;
    tmp[tid] = v;
    __syncthreads();
#pragma unroll
    for (int s = 1; s < 1024; s <<= 1) {
        int t = (tid >= s) ? tmp[tid - s] : 0;
        __syncthreads();
        tmp[tid] += t;
        __syncthreads();
    }
    if (tid < nb) bscan[tid] = tmp[tid] - v;
}

__global__ __launch_bounds__(256) void k_scan3(int* __restrict__ off,
        const int* __restrict__ bscan, const int* __restrict__ deg,
        int* __restrict__ cur, int n) {
    int i = blockIdx.x * 256 + threadIdx.x;
    if (i >= n) return;
    int o = off[i] + bscan[blockIdx.x];
    off[i] = o;
    cur[i] = o;
    if (i == n - 1) off[n] = o + deg[i];
}

// Fill CSR neighbor lists (grouped by destination, stores source index).
__global__ void k_fill(const int* __restrict__ row, const int* __restrict__ col,
                       int* __restrict__ cur, int* __restrict__ nbr, int E) {
    int e = blockIdx.x * 256 + threadIdx.x;
    if (e < E) {
        int c = col[e];
        int p = atomicAdd(&cur[c], 1);
        nbr[p] = row[e];
    }
}

// ---------------------------------------------------------------------------
// One-time weight transpose for coalesced phase-1 loads:
//   WT[k*192 + g*64 + j] = Wih[row(g,j)*64 + k],  g: 0->i (row j),
//   1->g (row 128+j), 2->o (row 192+j).  f-gate rows are dead (c0=0).
// ---------------------------------------------------------------------------
__global__ void k_tr(const float* __restrict__ Wih, float* __restrict__ WT) {
    int t = blockIdx.x * 256 + threadIdx.x;
    if (t >= 64 * 192) return;
    int k = t / 192, c = t % 192;
    int g = c >> 6, j = c & 63;
    int rowb = (g == 0) ? j : (g == 1) ? (128 + j) : (192 + j);
    WT[t] = Wih[rowb * 64 + k];
}

// ---------------------------------------------------------------------------
// Fused LSTM step + (h @ W1), GEMV-broadcast form.
// Wave owns 8 nodes; lane = output column.
// Phase 1 (gates): x rows staged per-wave in LDS as [k][8]; per k:
//   2x ds_read_b128 (uniform addr = broadcast) + 3 coalesced WT loads +
//   24 FMAs into 24 gate accumulators (no big per-thread arrays -> no spill).
// Transcendentals once per (node, lane-j).
// Phase 2 (h @ W1): h written back to the same LDS region (same-wave DS
// ordering, no barrier); lane = output col s; W1[j*64+s] coalesced.
// Grid: 12500 waves (~12/SIMD) vs 1563 in the per-thread version.
// ---------------------------------------------------------------------------
__global__ __launch_bounds__(256) void k_lstm_mm1(
    const float* __restrict__ x, const float* __restrict__ WT,
    const float* __restrict__ bih, const float* __restrict__ bhh,
    const float* __restrict__ W1, float* __restrict__ hw1, int n)
{
    __shared__ float4 xs[4][128];          // per-wave 2KB: [k][8 nodes] as 2xfloat4
    int wv   = threadIdx.x >> 6;
    int lane = threadIdx.x & 63;
    int nbase = (blockIdx.x * 4 + wv) * 8;
    if (nbase >= n) return;                // wave-uniform

    int ni[8];
#pragma unroll
    for (int m = 0; m < 8; m++) {
        int t = nbase + m;
        ni[m] = (t < n) ? t : (n - 1);     // clamp for safe loads
    }

    // stage x rows (coalesced global reads, per-wave LDS region)
    float xv[8];
#pragma unroll
    for (int m = 0; m < 8; m++) xv[m] = x[(size_t)ni[m] * 64 + lane];
    xs[wv][lane * 2 + 0] = make_float4(xv[0], xv[1], xv[2], xv[3]);
    xs[wv][lane * 2 + 1] = make_float4(xv[4], xv[5], xv[6], xv[7]);

    float gi[8], gg[8], go[8];
#pragma unroll
    for (int m = 0; m < 8; m++) { gi[m] = 0.f; gg[m] = 0.f; go[m] = 0.f; }

#pragma unroll 8
    for (int k = 0; k < 64; k++) {
        float4 xa = xs[wv][k * 2 + 0];     // broadcast
        float4 xb = xs[wv][k * 2 + 1];
        float wi = WT[k * 192 + lane];     // coalesced 256B
        float wg = WT[k * 192 + 64 + lane];
        float wo = WT[k * 192 + 128 + lane];
        gi[0] = fmaf(xa.x, wi, gi[0]); gi[1] = fmaf(xa.y, wi, gi[1]);
        gi[2] = fmaf(xa.z, wi, gi[2]); gi[3] = fmaf(xa.w, wi, gi[3]);
        gi[4] = fmaf(xb.x, wi, gi[4]); gi[5] = fmaf(xb.y, wi, gi[5]);
        gi[6] = fmaf(xb.z, wi, gi[6]); gi[7] = fmaf(xb.w, wi, gi[7]);
        gg[0] = fmaf(xa.x, wg, gg[0]); gg[1] = fmaf(xa.y, wg, gg[1]);
        gg[2] = fmaf(xa.z, wg, gg[2]); gg[3] = fmaf(xa.w, wg, gg[3]);
        gg[4] = fmaf(xb.x, wg, gg[4]); gg[5] = fmaf(xb.y, wg, gg[5]);
        gg[6] = fmaf(xb.z, wg, gg[6]); gg[7] = fmaf(xb.w, wg, gg[7]);
        go[0] = fmaf(xa.x, wo, go[0]); go[1] = fmaf(xa.y, wo, go[1]);
        go[2] = fmaf(xa.z, wo, go[2]); go[3] = fmaf(xa.w, wo, go[3]);
        go[4] = fmaf(xb.x, wo, go[4]); go[5] = fmaf(xb.y, wo, go[5]);
        go[6] = fmaf(xb.z, wo, go[6]); go[7] = fmaf(xb.w, wo, go[7]);
    }

    float bi = bih[lane]       + bhh[lane];
    float bg = bih[128 + lane] + bhh[128 + lane];
    float bo = bih[192 + lane] + bhh[192 + lane];

    float h[8];
#pragma unroll
    for (int m = 0; m < 8; m++) {
        float c = fast_sigmoid(gi[m] + bi) * fast_tanh(gg[m] + bg);
        h[m] = fast_sigmoid(go[m] + bo) * fast_tanh(c);
    }

    // reuse the same per-wave LDS region for h (same-wave DS order is safe)
    xs[wv][lane * 2 + 0] = make_float4(h[0], h[1], h[2], h[3]);
    xs[wv][lane * 2 + 1] = make_float4(h[4], h[5], h[6], h[7]);

    float acc[8];
#pragma unroll
    for (int m = 0; m < 8; m++) acc[m] = 0.f;

#pragma unroll 8
    for (int j = 0; j < 64; j++) {
        float4 ha = xs[wv][j * 2 + 0];     // broadcast
        float4 hb = xs[wv][j * 2 + 1];
        float w = W1[j * 64 + lane];       // coalesced 256B
        acc[0] = fmaf(ha.x, w, acc[0]); acc[1] = fmaf(ha.y, w, acc[1]);
        acc[2] = fmaf(ha.z, w, acc[2]); acc[3] = fmaf(ha.w, w, acc[3]);
        acc[4] = fmaf(hb.x, w, acc[4]); acc[5] = fmaf(hb.y, w, acc[5]);
        acc[6] = fmaf(hb.z, w, acc[6]); acc[7] = fmaf(hb.w, w, acc[7]);
    }

#pragma unroll
    for (int m = 0; m < 8; m++)
        if (nbase + m < n)
            hw1[(size_t)(nbase + m) * 64 + lane] = acc[m];
}

// ---------------------------------------------------------------------------
// Pull aggregation, F=64. One wave per node, lane = feature.
// Fused epilogue 1: h1 = relu(agg*dc + hw1[node]*dc^2 + b1)
// ---------------------------------------------------------------------------
__global__ __launch_bounds__(256) void k_pull64(
    const float* __restrict__ hw, const int* __restrict__ off,
    const int* __restrict__ nbr, const float* __restrict__ dinv,
    const float* __restrict__ b1, float* __restrict__ h1, int n)
{
    int node = (blockIdx.x * 256 + threadIdx.x) >> 6;
    int lane = threadIdx.x & 63;
    if (node >= n) return;
    int s = off[node], e = off[node + 1];
    float a0 = 0.0f, a1 = 0.0f;
    int j = s;
    for (; j + 2 <= e; j += 2) {           // 2 neighbors in flight
        int r0 = nbr[j], r1 = nbr[j + 1];
        float w0 = dinv[r0], w1 = dinv[r1];
        a0 = fmaf(hw[(size_t)r0 * 64 + lane], w0, a0);
        a1 = fmaf(hw[(size_t)r1 * 64 + lane], w1, a1);
    }
    if (j < e) {
        int r0 = nbr[j];
        a0 = fmaf(hw[(size_t)r0 * 64 + lane], dinv[r0], a0);
    }
    float dc   = dinv[node];
    float self = hw[(size_t)node * 64 + lane];
    float v = (a0 + a1) * dc + self * dc * dc + b1[lane];
    h1[(size_t)node * 64 + lane] = fmaxf(v, 0.0f);
}

// ---------------------------------------------------------------------------
// Pull aggregation, F=32. One wave per node; lanes 0-31 even neighbors,
// lanes 32-63 odd neighbors; halves combined via shfl_xor 32.
// Fused epilogue 2: z = agg*dc + hw2[node]*dc^2 + b2  (no relu)
// ---------------------------------------------------------------------------
__global__ __launch_bounds__(256) void k_pull32(
    const float* __restrict__ hw, const int* __restrict__ off,
    const int* __restrict__ nbr, const float* __restrict__ dinv,
    const float* __restrict__ b2, float* __restrict__ z, int n)
{
    int node = (blockIdx.x * 256 + threadIdx.x) >> 6;
    int lane = threadIdx.x & 63;
    int feat = lane & 31;
    int half = lane >> 5;
    if (node >= n) return;
    int s = off[node], e = off[node + 1];
    float acc = 0.0f;
    for (int j = s + half; j < e; j += 2) {
        int r = nbr[j];
        acc = fmaf(hw[(size_t)r * 32 + feat], dinv[r], acc);
    }
    acc += __shfl_xor(acc, 32, 64);        // combine even/odd halves
    float dc = dinv[node];
    float v = acc * dc + hw[(size_t)node * 32 + feat] * dc * dc + b2[feat];
    if (half == 0) z[(size_t)node * 32 + feat] = v;
}

// ---------------------------------------------------------------------------
// hw2 = h1 @ W2  ([n,64] x [64,32]). Block = 128 nodes, h1 tile in LDS (pad 65).
// ---------------------------------------------------------------------------
__global__ __launch_bounds__(128) void k_mm2(
    const float* __restrict__ h1, const float* __restrict__ W2,
    float* __restrict__ hw2, int n)
{
    __shared__ float tile[128 * 65];
    int base  = blockIdx.x * 128;
    int nrows = n - base; if (nrows > 128) nrows = 128;

    for (int idx = threadIdx.x; idx < nrows * 64; idx += 128) {
        int r = idx >> 6, c = idx & 63;
        tile[r * 65 + c] = h1[(size_t)base * 64 + idx];
    }
    __syncthreads();

    int node = base + threadIdx.x;
    if (node >= n) return;

    const float* hrow = &tile[threadIdx.x * 65];
    float acc[32];
#pragma unroll
    for (int s = 0; s < 32; s++) acc[s] = 0.0f;

    for (int k = 0; k < 64; k++) {
        float hk = hrow[k];
        const float* w = W2 + (size_t)k * 32;
#pragma unroll
        for (int s = 0; s < 32; s++) acc[s] = fmaf(hk, w[s], acc[s]);
    }

    float4* op = reinterpret_cast<float4*>(hw2 + (size_t)node * 32);
#pragma unroll
    for (int q = 0; q < 8; q++)
        op[q] = make_float4(acc[4*q], acc[4*q+1], acc[4*q+2], acc[4*q+3]);
}

// ---------------------------------------------------------------------------
// out[e] = dot(z[src[e]], z[dst[e]]) over 32 features
// ---------------------------------------------------------------------------
__global__ void k_dot(const float* __restrict__ z, const int* __restrict__ src,
                      const int* __restrict__ dst, float* __restrict__ out, int EL)
{
    int e = blockIdx.x * 256 + threadIdx.x;
    if (e >= EL) return;
    const float4* a = reinterpret_cast<const float4*>(z + (size_t)src[e] * 32);
    const float4* b = reinterpret_cast<const float4*>(z + (size_t)dst[e] * 32);
    float s = 0.0f;
#pragma unroll
    for (int q = 0; q < 8; q++) {
        float4 av = a[q], bv = b[q];
        s = fmaf(av.x, bv.x, s);
        s = fmaf(av.y, bv.y, s);
        s = fmaf(av.z, bv.z, s);
        s = fmaf(av.w, bv.w, s);
    }
    out[e] = s;
}

extern "C" void kernel_launch(void* const* d_in, const int* in_sizes, int n_in,
                              void* d_out, int out_size, void* d_ws, size_t ws_size,
                              hipStream_t stream)
{
    const float* x   = (const float*)d_in[0];
    const int*   ei  = (const int*)d_in[1];
    const int*   eli = (const int*)d_in[2];
    const float* Wih = (const float*)d_in[3];
    // d_in[4] = W_hh: mathematically dead (h0 = c0 = 0)
    const float* bih = (const float*)d_in[5];
    const float* bhh = (const float*)d_in[6];
    const float* W1  = (const float*)d_in[7];
    const float* b1  = (const float*)d_in[8];
    const float* W2  = (const float*)d_in[9];
    const float* b2  = (const float*)d_in[10];

    int n  = in_sizes[0] / 64;
    int E  = in_sizes[1] / 2;
    int EL = in_sizes[2] / 2;

    const int* row  = ei;          // source
    const int* col  = ei + E;      // destination
    const int* lsrc = eli;
    const int* ldst = eli + EL;
    float* out = (float*)d_out;

    // Workspace layout (4B units), liveness-aliased:
    //   bufA [n*64]: hw1 (lstm..pull64), then hw2 in first n*32 (mm2..pull32)
    //   bufB [n*64]: h1  (pull64..mm2), then z   in first n*32 (pull32..dot)
    //   dinv [n] | off [n+1] | deg [n] | cur [n] | bsum [1024] | bscan [1024]
    //   nbr [E] | WT [64*192]   (~59.3 MB total)
    float* bufA  = (float*)d_ws;
    float* bufB  = bufA + (size_t)n * 64;
    float* dinv  = bufB + (size_t)n * 64;
    int*   off   = (int*)(dinv + n);
    int*   deg   = off + (n + 1);
    int*   cur   = deg + n;
    int*   bsum  = cur + n;
    int*   bscan = bsum + 1024;
    int*   nbr   = bscan + 1024;
    float* WT    = (float*)(nbr + E);

    int nb = (n + 255) / 256;      // 391 for n=100000; k_scan2 handles nb<=1024
    dim3 blk(256);

    // --- weight transpose for LSTM phase-1 (tiny, one-time per call) ---
    k_tr<<<dim3((64 * 192 + 255) / 256), blk, 0, stream>>>(Wih, WT);

    // --- CSR build (deterministic counting sort by destination) ---
    hipMemsetAsync(deg, 0, (size_t)n * sizeof(int), stream);
    k_deg  <<<dim3((E + 255) / 256), blk, 0, stream>>>(col, deg, E);
    k_dinv <<<dim3(nb), blk, 0, stream>>>(deg, dinv, n);
    k_scan1<<<dim3(nb), blk, 0, stream>>>(deg, off, bsum, n);
    k_scan2<<<dim3(1), dim3(1024), 0, stream>>>(bsum, bscan, nb);
    k_scan3<<<dim3(nb), blk, 0, stream>>>(off, bscan, deg, cur, n);
    k_fill <<<dim3((E + 255) / 256), blk, 0, stream>>>(row, col, cur, nbr, E);

    // --- LSTM + first matmul: hw1 -> bufA (8 nodes/wave, 32 nodes/block) ---
    {
        int blocks = (n + 31) / 32;
        k_lstm_mm1<<<dim3(blocks), blk, 0, stream>>>(x, WT, bih, bhh, W1, bufA, n);
    }

    // --- GCN1: pull + fused epilogue (relu) : h1 -> bufB ---
    {
        int blocks = (int)(((size_t)n * 64 + 255) / 256);
        k_pull64<<<dim3(blocks), blk, 0, stream>>>(bufA, off, nbr, dinv, b1, bufB, n);
    }

    // --- second matmul: hw2 -> bufA (hw1 dead) ---
    k_mm2<<<dim3((n + 127) / 128), dim3(128), 0, stream>>>(bufB, W2, bufA, n);

    // --- GCN2: pull + fused epilogue : z -> bufB (h1 dead) ---
    {
        int blocks = (int)(((size_t)n * 64 + 255) / 256);
        k_pull32<<<dim3(blocks), blk, 0, stream>>>(bufA, off, nbr, dinv, b2, bufB, n);
    }

    // --- edge dot products ---
    k_dot<<<dim3((EL + 255) / 256), blk, 0, stream>>>(bufB, lsrc, ldst, out, EL);
}